// Round 12
// baseline (51.019 us; speedup 1.0000x reference)
//
#include <hip/hip_runtime.h>
#include <hip/hip_bf16.h>

#define BSZ   4096
#define NCON  8192
#define DFEAT 256
#define INV_T 14.285714285714285f   // 1/T; analytic row max (self-dot==1) folded in

#define BJ 32                 // j-tile width (per LDS panel)
#define BI 128                // i-rows per block (4 waves x 32)
#define NJT 8                 // j-tiles per block
#define JSTRIP (NJT * BJ)     // 256 contrast cols per block

typedef __attribute__((ext_vector_type(8))) short short8;
typedef __attribute__((ext_vector_type(4))) float f32x4;

__device__ __forceinline__ unsigned short f2bf(float f) {
    __hip_bfloat16 h = __float2bfloat16(f);
    return *reinterpret_cast<unsigned short*>(&h);
}

__device__ __forceinline__ void gload_lds16(const void* g, void* l) {
    __builtin_amdgcn_global_load_lds(
        (const __attribute__((address_space(1))) unsigned int*)g,
        (__attribute__((address_space(3))) unsigned int*)l,
        16, 0, 0);
}

// Volatile asm load: cannot be rematerialized/sunk — keeps Y register-resident.
__device__ __forceinline__ void gload_reg16(const void* p, short8& dst) {
    unsigned long long a = (unsigned long long)p;
    asm volatile("global_load_dwordx4 %0, %1, off"
                 : "=v"(dst) : "v"(a));
}

// ws layout: [0, 4MB) contrast bf16 [NCON][DFEAT]; then f32 S[4096], A[4096], B[4096]

__global__ __launch_bounds__(256) void k_prep(const float* __restrict__ feat,
                                              unsigned short* __restrict__ con,
                                              float* __restrict__ acc) {
    int idx = blockIdx.x * 256 + threadIdx.x;
    int e = idx * 4;
    int j = e >> 8;
    int k = e & 255;
    int src = (j < BSZ) ? ((j * 2) * DFEAT + k)
                        : (((j - BSZ) * 2 + 1) * DFEAT + k);
    float4 f = *(const float4*)(feat + src);
    ushort4 o;
    o.x = f2bf(f.x); o.y = f2bf(f.y); o.z = f2bf(f.z); o.w = f2bf(f.w);
    *(ushort4*)(con + e) = o;
    if (idx < 3 * BSZ) acc[idx] = 0.0f;
}

// lX panel (16 KB): 4 sub-panels [k2][row 0..31][64 cols], 128B row stride —
// same row-stride/swizzle pattern that measured 0 bank conflicts.
__global__ __launch_bounds__(256, 2) void k_main(const __hip_bfloat16* __restrict__ conp,
                                                 const float* __restrict__ va,
                                                 const int* __restrict__ dia,
                                                 const int* __restrict__ thr_ptr,
                                                 float* __restrict__ Srow,
                                                 float* __restrict__ Arow,
                                                 float* __restrict__ Brow) {
    __shared__ short lX[2][BJ * DFEAT];          // 2 x 16 KB, double-buffered
    __shared__ float s_vjx[JSTRIP], s_vjy[JSTRIP];
    __shared__ int   s_dj[JSTRIP];

    const int tid  = threadIdx.x;
    const int lane = tid & 63;
    const int wv   = tid >> 6;
    const int l15  = lane & 15;
    const int hi   = lane >> 4;
    const int jstrip0 = blockIdx.x * JSTRIP;        // [0, 8192)
    const int ibase   = blockIdx.y * BI + wv * 32;  // this wave's 32 anchor rows
    const short* cs = (const short*)conp;

    auto stageX = [&](int buf, int jt) {
        #pragma unroll
        for (int q = 0; q < 4; ++q) {
            int e   = q * 2048 + tid * 8;      // element in [0, 8192)
            int col = e & 63;
            int row = (e >> 6) & 31;
            int k2  = e >> 11;                 // 64-col sub-panel (0..3)
            int scol = col ^ ((row & 7) << 3); // involution pre-swizzle
            gload_lds16(cs + (size_t)(jstrip0 + jt * BJ + row) * DFEAT + k2 * 64 + scol,
                        &lX[buf][e]);
        }
    };

    stageX(0, 0);

    // ---- Y panel to registers (volatile asm; 64 regs, resident) ----
    const short* yrow0 = cs + (size_t)(ibase + l15) * DFEAT + hi * 8;
    short8 y[2][8];
    #pragma unroll
    for (int n = 0; n < 2; ++n)
        #pragma unroll
        for (int s = 0; s < 8; ++s)
            gload_reg16(yrow0 + (size_t)n * 16 * DFEAT + s * 32, y[n][s]);

    // ---- strip metadata (256 j entries) ----
    if (tid < JSTRIP) {
        int jm = (jstrip0 + tid) & (BSZ - 1);
        s_vjx[tid] = va[2 * jm]; s_vjy[tid] = va[2 * jm + 1]; s_dj[tid] = dia[jm];
    }

    int raw = *thr_ptr;
    float t_ = (raw > 0 && raw < 100000) ? (float)raw : __int_as_float(raw);
    float thres2 = t_ * t_;

    float vix[2], viy[2]; int di[2];
    #pragma unroll
    for (int n = 0; n < 2; ++n) {
        int i = ibase + n * 16 + l15;
        vix[n] = va[2 * i]; viy[n] = va[2 * i + 1]; di[n] = dia[i];
    }

    float sp[2] = {0.f, 0.f};
    float ap[2] = {0.f, 0.f};
    float bp[2] = {0.f, 0.f};

    __syncthreads();                                   // drains staging + Y loads
    asm volatile("s_waitcnt vmcnt(0)" ::: "memory");
    __builtin_amdgcn_sched_barrier(0);

    for (int jt = 0; jt < NJT; ++jt) {
        const int cur = jt & 1;
        if (jt < NJT - 1) stageX(cur ^ 1, jt + 1);     // stream next tile under compute

        f32x4 acc[2][2];
        #pragma unroll
        for (int m = 0; m < 2; ++m)
            #pragma unroll
            for (int n = 0; n < 2; ++n)
                acc[m][n] = (f32x4){0.f, 0.f, 0.f, 0.f};

        const char* bufX = (const char*)&lX[cur][0];
        #pragma unroll
        for (int s = 0; s < 8; ++s) {
            const int base = (s >> 1) * 4096;          // sub-panel byte base (32x128B)
            const int colb = (s & 1) * 64 + hi * 16;   // byte col in sub-panel
            short8 xf[2];
            #pragma unroll
            for (int m = 0; m < 2; ++m) {
                int row = m * 16 + l15;
                xf[m] = *(const short8*)(bufX + base + row * 128 + (colb ^ ((row & 7) << 4)));
            }
            #pragma unroll
            for (int m = 0; m < 2; ++m)
                #pragma unroll
                for (int n = 0; n < 2; ++n)
                    acc[m][n] = __builtin_amdgcn_mfma_f32_16x16x32_bf16(xf[m], y[n][s], acc[m][n], 0, 0, 0);
        }

        // epilogue for this tile: registers + loop-invariant LDS metadata only
        const int jt0 = jt * BJ;
        #pragma unroll
        for (int m = 0; m < 2; ++m) {
            #pragma unroll
            for (int r = 0; r < 4; ++r) {
                const int jl = m * 16 + hi * 4 + r;
                const int j  = jstrip0 + jt0 + jl;
                const int jm = j & (BSZ - 1);
                float vjx = s_vjx[jt0 + jl], vjy = s_vjy[jt0 + jl];
                int dj = s_dj[jt0 + jl];
                #pragma unroll
                for (int n = 0; n < 2; ++n) {
                    const int i = ibase + n * 16 + l15;
                    float l = __builtin_fmaf(acc[m][n][r], INV_T, -INV_T);  // logits - max
                    bool lm = (j != i);
                    float e = lm ? __expf(l) : 0.0f;                        // native v_exp
                    float dx = vix[n] - vjx, dy = viy[n] - vjy;
                    bool mk = (i == jm) | (di[n] == dj) | (dx * dx + dy * dy < thres2);
                    sp[n] += e;
                    if (mk & lm) { ap[n] += l; bp[n] += 1.0f; }
                }
            }
        }
        __syncthreads();   // next iter overwrites the buffer we just computed from
    }

    // ---- one reduction + atomic set per block ----
    #pragma unroll
    for (int n = 0; n < 2; ++n) {
        float s = sp[n], a = ap[n], b = bp[n];
        s += __shfl_xor(s, 16, 64);  a += __shfl_xor(a, 16, 64);  b += __shfl_xor(b, 16, 64);
        s += __shfl_xor(s, 32, 64);  a += __shfl_xor(a, 32, 64);  b += __shfl_xor(b, 32, 64);
        if (hi == 0) {
            int i = ibase + n * 16 + l15;
            atomicAdd(&Srow[i], s);
            atomicAdd(&Arow[i], a);
            atomicAdd(&Brow[i], b);
        }
    }
}

__global__ __launch_bounds__(256) void k_final(const float* __restrict__ S,
                                               const float* __restrict__ A,
                                               const float* __restrict__ B,
                                               float* __restrict__ out) {
    __shared__ float red[256];
    float sum = 0.f;
    for (int i = threadIdx.x; i < BSZ; i += 256) {
        float b = B[i];
        float v = (A[i] - b * logf(S[i] + 1e-10f)) / (b + 1e-10f);
        sum += -v;
    }
    red[threadIdx.x] = sum;
    __syncthreads();
    for (int s = 128; s > 0; s >>= 1) {
        if (threadIdx.x < s) red[threadIdx.x] += red[threadIdx.x + s];
        __syncthreads();
    }
    if (threadIdx.x == 0) out[0] = red[0] / (float)BSZ;
}

extern "C" void kernel_launch(void* const* d_in, const int* in_sizes, int n_in,
                              void* d_out, int out_size, void* d_ws, size_t ws_size,
                              hipStream_t stream) {
    const float* feat = (const float*)d_in[0];
    const float* va   = (const float*)d_in[1];
    const int*   dia  = (const int*)d_in[2];
    const int*   thr  = (const int*)d_in[3];

    unsigned short* con = (unsigned short*)d_ws;
    float* acc = (float*)((char*)d_ws + (size_t)NCON * DFEAT * 2);
    float* out = (float*)d_out;

    k_prep<<<(NCON * DFEAT / 4 + 255) / 256, 256, 0, stream>>>(feat, con, acc);

    dim3 grid(NCON / JSTRIP, BSZ / BI);   // (32, 32) = 1024 blocks = 4/CU
    k_main<<<grid, 256, 0, stream>>>((const __hip_bfloat16*)con, va, dia, thr,
                                     acc, acc + BSZ, acc + 2 * BSZ);

    k_final<<<1, 256, 0, stream>>>(acc, acc + BSZ, acc + 2 * BSZ, out);
}

// Round 13
// 43.549 us; speedup vs baseline: 1.1715x; 1.1715x over previous
//
#include <hip/hip_runtime.h>
#include <hip/hip_bf16.h>

#define BSZ   4096
#define NCON  8192
#define DFEAT 256
#define INV_T 14.285714285714285f   // 1/T; analytic row max (self-dot==1) folded in

#define BJM 32                // jm per tile (each tile covers cols jm AND jm+4096)
#define BI 128                // i-rows per block (4 waves x 32)
#define NJT 8                 // jm-tiles per block
#define JSTRIP_M (NJT * BJM)  // 256 jm per block (512 logit-cols)

typedef __attribute__((ext_vector_type(8))) short short8;
typedef __attribute__((ext_vector_type(4))) float f32x4;

__device__ __forceinline__ unsigned short f2bf(float f) {
    __hip_bfloat16 h = __float2bfloat16(f);
    return *reinterpret_cast<unsigned short*>(&h);
}

__device__ __forceinline__ void gload_lds16(const void* g, void* l) {
    __builtin_amdgcn_global_load_lds(
        (const __attribute__((address_space(1))) unsigned int*)g,
        (__attribute__((address_space(3))) unsigned int*)l,
        16, 0, 0);
}

// Volatile asm load: cannot be rematerialized/sunk — keeps Y register-resident.
__device__ __forceinline__ void gload_reg16(const void* p, short8& dst) {
    unsigned long long a = (unsigned long long)p;
    asm volatile("global_load_dwordx4 %0, %1, off"
                 : "=v"(dst) : "v"(a));
}

// ws layout: [0, 4MB) contrast bf16 [NCON][DFEAT]; then f32 S[4096], A[4096], B[4096]

__global__ __launch_bounds__(256) void k_prep(const float* __restrict__ feat,
                                              unsigned short* __restrict__ con,
                                              float* __restrict__ acc) {
    int idx = blockIdx.x * 256 + threadIdx.x;
    int e = idx * 4;
    int j = e >> 8;
    int k = e & 255;
    int src = (j < BSZ) ? ((j * 2) * DFEAT + k)
                        : (((j - BSZ) * 2 + 1) * DFEAT + k);
    float4 f = *(const float4*)(feat + src);
    ushort4 o;
    o.x = f2bf(f.x); o.y = f2bf(f.y); o.z = f2bf(f.z); o.w = f2bf(f.w);
    *(ushort4*)(con + e) = o;
    if (idx < 3 * BSZ) acc[idx] = 0.0f;
}

// lX panel per view (16 KB): 4 sub-panels [k2][row 0..31][64 cols], 128B row
// stride — same swizzle that measured 0 bank conflicts.
__global__ __launch_bounds__(256, 2) void k_main(const __hip_bfloat16* __restrict__ conp,
                                                 const float* __restrict__ va,
                                                 const int* __restrict__ dia,
                                                 const int* __restrict__ thr_ptr,
                                                 float* __restrict__ Srow,
                                                 float* __restrict__ Arow,
                                                 float* __restrict__ Brow) {
    __shared__ short lX[2][2][BJM * DFEAT];      // [dbuf][view][8192] = 64 KB
    __shared__ float s_vjx[JSTRIP_M], s_vjy[JSTRIP_M];
    __shared__ int   s_dj[JSTRIP_M];

    const int tid  = threadIdx.x;
    const int lane = tid & 63;
    const int wv   = tid >> 6;
    const int l15  = lane & 15;
    const int hi   = lane >> 4;
    const int jmbase = blockIdx.x * JSTRIP_M;       // [0, 4096)
    const int ibase  = blockIdx.y * BI + wv * 32;   // this wave's 32 anchor rows
    const short* cs = (const short*)conp;

    auto stageX = [&](int buf, int jt) {
        #pragma unroll
        for (int v = 0; v < 2; ++v) {
            #pragma unroll
            for (int q = 0; q < 4; ++q) {
                int e   = q * 2048 + tid * 8;      // element in [0, 8192)
                int col = e & 63;
                int row = (e >> 6) & 31;
                int k2  = e >> 11;                 // 64-col sub-panel (0..3)
                int scol = col ^ ((row & 7) << 3); // involution pre-swizzle
                gload_lds16(cs + (size_t)(jmbase + jt * BJM + row + v * BSZ) * DFEAT
                               + k2 * 64 + scol,
                            &lX[buf][v][e]);
            }
        }
    };

    stageX(0, 0);

    // ---- Y panel to registers (volatile asm; 64 regs, resident) ----
    const short* yrow0 = cs + (size_t)(ibase + l15) * DFEAT + hi * 8;
    short8 y[2][8];
    #pragma unroll
    for (int n = 0; n < 2; ++n)
        #pragma unroll
        for (int s = 0; s < 8; ++s)
            gload_reg16(yrow0 + (size_t)n * 16 * DFEAT + s * 32, y[n][s]);

    // ---- strip metadata (256 jm entries) ----
    if (tid < JSTRIP_M) {
        int jm = jmbase + tid;
        s_vjx[tid] = va[2 * jm]; s_vjy[tid] = va[2 * jm + 1]; s_dj[tid] = dia[jm];
    }

    int raw = *thr_ptr;
    float t_ = (raw > 0 && raw < 100000) ? (float)raw : __int_as_float(raw);
    float thres2 = t_ * t_;

    float vix[2], viy[2]; int di[2];
    #pragma unroll
    for (int n = 0; n < 2; ++n) {
        int i = ibase + n * 16 + l15;
        vix[n] = va[2 * i]; viy[n] = va[2 * i + 1]; di[n] = dia[i];
    }

    float sp[2] = {0.f, 0.f};
    float ap[2] = {0.f, 0.f};
    float bp[2] = {0.f, 0.f};

    __syncthreads();                                   // drains staging + Y loads
    asm volatile("s_waitcnt vmcnt(0)" ::: "memory");
    __builtin_amdgcn_sched_barrier(0);

    for (int jt = 0; jt < NJT; ++jt) {
        const int cur = jt & 1;
        if (jt < NJT - 1) stageX(cur ^ 1, jt + 1);     // stream next tile under compute

        f32x4 acc[2][2][2];   // [view][m = jm-frag][n = i-frag]
        #pragma unroll
        for (int v = 0; v < 2; ++v)
            #pragma unroll
            for (int m = 0; m < 2; ++m)
                #pragma unroll
                for (int n = 0; n < 2; ++n)
                    acc[v][m][n] = (f32x4){0.f, 0.f, 0.f, 0.f};

        #pragma unroll
        for (int s = 0; s < 8; ++s) {
            const int base = (s >> 1) * 4096;          // sub-panel byte base (32x128B)
            const int colb = (s & 1) * 64 + hi * 16;   // byte col in sub-panel
            short8 xf[2][2];
            #pragma unroll
            for (int v = 0; v < 2; ++v)
                #pragma unroll
                for (int m = 0; m < 2; ++m) {
                    int row = m * 16 + l15;
                    xf[v][m] = *(const short8*)((const char*)&lX[cur][v][0]
                                 + base + row * 128 + (colb ^ ((row & 7) << 4)));
                }
            #pragma unroll
            for (int v = 0; v < 2; ++v)
                #pragma unroll
                for (int m = 0; m < 2; ++m)
                    #pragma unroll
                    for (int n = 0; n < 2; ++n)
                        acc[v][m][n] = __builtin_amdgcn_mfma_f32_16x16x32_bf16(
                            xf[v][m], y[n][s], acc[v][m][n], 0, 0, 0);
        }

        // epilogue: mask computed ONCE per (i, jm), applied to both views
        const int jt0 = jt * BJM;
        #pragma unroll
        for (int m = 0; m < 2; ++m) {
            #pragma unroll
            for (int r = 0; r < 4; ++r) {
                const int jl  = jt0 + m * 16 + hi * 4 + r;   // local jm in strip
                const int jmg = jmbase + jl;                 // global jm [0,4096)
                float vjx = s_vjx[jl], vjy = s_vjy[jl];
                int dj = s_dj[jl];
                #pragma unroll
                for (int n = 0; n < 2; ++n) {
                    const int i = ibase + n * 16 + l15;
                    float a0 = acc[0][m][n][r], a1 = acc[1][m][n][r];
                    float l0 = __builtin_fmaf(a0, INV_T, -INV_T);
                    float l1 = __builtin_fmaf(a1, INV_T, -INV_T);
                    float dx = vix[n] - vjx, dy = viy[n] - vjy;
                    bool diag = (i == jmg);
                    bool mk = diag | (di[n] == dj) | (dx * dx + dy * dy < thres2);
                    float e0 = diag ? 0.0f : __expf(l0);     // logits_mask kills diagonal
                    float e1 = __expf(l1);                   // view1 col never diagonal
                    sp[n] += e0 + e1;
                    float msel  = mk ? 1.0f : 0.0f;          // mask_t for view1 col
                    float msel0 = (mk & !diag) ? 1.0f : 0.0f; // mask_t for view0 col
                    ap[n] = __builtin_fmaf(msel0, l0, ap[n]);
                    ap[n] = __builtin_fmaf(msel,  l1, ap[n]);
                    bp[n] += msel0 + msel;
                }
            }
        }
        __syncthreads();   // next iter overwrites the buffer we just computed from
    }

    // ---- one reduction + atomic set per block ----
    #pragma unroll
    for (int n = 0; n < 2; ++n) {
        float s = sp[n], a = ap[n], b = bp[n];
        s += __shfl_xor(s, 16, 64);  a += __shfl_xor(a, 16, 64);  b += __shfl_xor(b, 16, 64);
        s += __shfl_xor(s, 32, 64);  a += __shfl_xor(a, 32, 64);  b += __shfl_xor(b, 32, 64);
        if (hi == 0) {
            int i = ibase + n * 16 + l15;
            atomicAdd(&Srow[i], s);
            atomicAdd(&Arow[i], a);
            atomicAdd(&Brow[i], b);
        }
    }
}

__global__ __launch_bounds__(256) void k_final(const float* __restrict__ S,
                                               const float* __restrict__ A,
                                               const float* __restrict__ B,
                                               float* __restrict__ out) {
    __shared__ float red[256];
    float sum = 0.f;
    for (int i = threadIdx.x; i < BSZ; i += 256) {
        float b = B[i];
        float v = (A[i] - b * logf(S[i] + 1e-10f)) / (b + 1e-10f);
        sum += -v;
    }
    red[threadIdx.x] = sum;
    __syncthreads();
    for (int s = 128; s > 0; s >>= 1) {
        if (threadIdx.x < s) red[threadIdx.x] += red[threadIdx.x + s];
        __syncthreads();
    }
    if (threadIdx.x == 0) out[0] = red[0] / (float)BSZ;
}

extern "C" void kernel_launch(void* const* d_in, const int* in_sizes, int n_in,
                              void* d_out, int out_size, void* d_ws, size_t ws_size,
                              hipStream_t stream) {
    const float* feat = (const float*)d_in[0];
    const float* va   = (const float*)d_in[1];
    const int*   dia  = (const int*)d_in[2];
    const int*   thr  = (const int*)d_in[3];

    unsigned short* con = (unsigned short*)d_ws;
    float* acc = (float*)((char*)d_ws + (size_t)NCON * DFEAT * 2);
    float* out = (float*)d_out;

    k_prep<<<(NCON * DFEAT / 4 + 255) / 256, 256, 0, stream>>>(feat, con, acc);

    dim3 grid(BSZ / JSTRIP_M, BSZ / BI);   // (16, 32) = 512 blocks
    k_main<<<grid, 256, 0, stream>>>((const __hip_bfloat16*)con, va, dia, thr,
                                     acc, acc + BSZ, acc + 2 * BSZ);

    k_final<<<1, 256, 0, stream>>>(acc, acc + BSZ, acc + 2 * BSZ, out);
}